// Round 2
// baseline (19636.465 us; speedup 1.0000x reference)
//
#include <hip/hip_runtime.h>
#include <math.h>

// Problem constants (from setup_inputs)
#define NSEQ 8192
#define DH 512
#define DZ 128
#define DE 128
#define VOCAB 64
#define TMAX 80
#define SOS 1
#define EOS_TOK 2

// GEMM tiling: 128 rows x (3 gates x 64 cols) per block, K-chunk 32, 8 waves.
// Wave w: rows [(w>>1)*32, +32), cols per gate [(w&1)*32, +32) of the block's 64.
#define TMR 128

typedef _Float16 half_t;
typedef half_t h8 __attribute__((ext_vector_type(8)));
typedef float f16v __attribute__((ext_vector_type(16)));

__device__ __forceinline__ float sigf(float x) { return 1.0f / (1.0f + expf(-x)); }

// fp32 -> f16x2 split: v ~= hi + lo/2048, both RN. hi forced to 0 below f16
// min-normal so MFMA denorm behavior can't drop it (lo then carries v*2048,
// which is normal). Representation error <= 2^-22 |v|.
__device__ __forceinline__ void split2(float v, half_t& hi, half_t& lo) {
    float hf = (float)(half_t)v;
    if (fabsf(v) < 6.2e-5f) hf = 0.0f;
    hi = (half_t)hf;
    lo = (half_t)((v - hf) * 2048.0f);
}

__device__ __forceinline__ float rec2(half_t h, half_t l) {
    return (float)h + (float)l * (1.0f / 2048.0f);
}

__device__ __forceinline__ void gl_lds16(const void* g, void* l) {
    __builtin_amdgcn_global_load_lds((const __attribute__((address_space(1))) void*)g,
                                     (__attribute__((address_space(3))) void*)l, 16, 0, 0);
}

// XCD-aware swizzle: bid (0..511) -> row-tile 0..63, col-tile 0..7. Same-XCD
// blocks share row-tiles (A panels L2-resident per XCD). Bijective.
__device__ __forceinline__ void swz(int bid, int& r, int& c) {
    const int x = bid & 7;
    const int q = bid >> 3;       // 0..63
    r = (q & 7) * 8 + x;          // 0..63
    c = q >> 3;                   // 0..7
}

// ---------------------------------------------------------------- init
__global__ __launch_bounds__(256) void init_kernel(int* __restrict__ x_prev,
                                                   int* __restrict__ eos,
                                                   int* __restrict__ out,
                                                   int* __restrict__ list,
                                                   int* __restrict__ count) {
    int i = blockIdx.x * 256 + threadIdx.x;
    x_prev[i] = SOS;
    eos[i] = 0;
    list[i] = i;
    out[i * TMAX] = SOS;
    out[NSEQ * TMAX + i] = TMAX;
    if (i == 0) count[0] = NSEQ;
}

// ---------------------------------------------------------------- active-row compaction (pad to 128)
__global__ __launch_bounds__(1024) void compact_kernel(const int* __restrict__ eos,
                                                       int* __restrict__ list,
                                                       int* __restrict__ count) {
    __shared__ int part[1024];
    __shared__ int slist[NSEQ];
    const int tid = threadIdx.x;
    const int base = tid * 8;
    int f[8], s = 0;
#pragma unroll
    for (int i = 0; i < 8; ++i) { f[i] = eos[base + i] ? 0 : 1; s += f[i]; }
    part[tid] = s;
    __syncthreads();
    for (int off = 1; off < 1024; off <<= 1) {
        int v = (tid >= off) ? part[tid - off] : 0;
        __syncthreads();
        part[tid] += v;
        __syncthreads();
    }
    const int total = part[1023];
    int p = part[tid] - s;   // exclusive prefix
#pragma unroll
    for (int i = 0; i < 8; ++i) if (f[i]) slist[p++] = base + i;
    __syncthreads();
    if (tid == 0) {
        count[0] = total;
        if (total > 0) {
            const int last = slist[total - 1];
            const int padn = (total + 127) & ~127;
            for (int k = total; k < padn; ++k) slist[k] = last;
        }
    }
    __syncthreads();
    const int padn = (total + 127) & ~127;
    for (int k = tid; k < padn; k += 1024) list[k] = slist[k];
}

// ---------------------------------------------------------------- h0 = Z @ z2h_w.T + b (fp64 acc) -> f16x2 splits x3 buffers
__global__ __launch_bounds__(256) void h0_kernel(const float* __restrict__ Z,
                                                 const float* __restrict__ w,
                                                 const float* __restrict__ b,
                                                 half_t* __restrict__ B0h, half_t* __restrict__ B0l,
                                                 half_t* __restrict__ B1h, half_t* __restrict__ B1l,
                                                 half_t* __restrict__ B2h, half_t* __restrict__ B2l) {
    __shared__ float zrow[DZ];
    const int i = blockIdx.x;
    const int tid = threadIdx.x;
    if (tid < DZ) zrow[tid] = Z[(size_t)i * DZ + tid];
    __syncthreads();
    for (int j = tid; j < DH; j += 256) {
        double s = (double)b[j];
        const float* wr = w + (size_t)j * DZ;
#pragma unroll 8
        for (int k = 0; k < DZ; ++k) s += (double)zrow[k] * (double)wr[k];
        float sf = (float)s;
        half_t hi, lo;
        split2(sf, hi, lo);
        size_t o = (size_t)i * DH + j;
        B0h[o] = hi; B0l[o] = lo;
        B1h[o] = hi; B1l[o] = lo;
        B2h[o] = hi; B2l[o] = lo;
    }
}

// ---------------------------------------------------------------- gi0 table (fp64)
__global__ __launch_bounds__(256) void gi0_kernel(const float* __restrict__ emb,
                                                  const float* __restrict__ w_ih0,
                                                  const float* __restrict__ b_ih0,
                                                  double* __restrict__ tab) {
    __shared__ float e[DE];
    const int x = blockIdx.x;
    const int tid = threadIdx.x;
    if (tid < DE) e[tid] = emb[(size_t)x * DE + tid];
    __syncthreads();
    for (int j = tid; j < 3 * DH; j += 256) {
        double s = (double)b_ih0[j];
        const float* wr = w_ih0 + (size_t)j * DE;
#pragma unroll 8
        for (int k = 0; k < DE; ++k) s += (double)e[k] * (double)wr[k];
        tab[(size_t)x * 3 * DH + j] = s;
    }
}

// ---------------------------------------------------------------- weight split fp32 -> f16 hi/lo
__global__ __launch_bounds__(256) void wsplit_kernel(const float* __restrict__ w,
                                                     half_t* __restrict__ hi,
                                                     half_t* __restrict__ lo, int n) {
    int i = blockIdx.x * 256 + threadIdx.x;
    if (i < n) {
        half_t h, l;
        split2(w[i], h, l);
        hi[i] = h; lo[i] = l;
    }
}

// LDS layout per buffer (40960 B): [0,8192) A_hi, [8192,16384) A_lo,
// [16384,28672) B_hi, [28672,40960) B_lo. Element (row,kchunk8) lives at
// (row>>3)*512 + kchunk*128 + (row&7)*16 within its region (16B = 8 f16).
// This makes both the global_load_lds dest (linear in tid) and the
// ds_read_b128 fragment reads (8 consecutive 16B slots per 8-lane group)
// conflict-free with no XOR swizzle. Two buffers: 0 and 40960.

// ---------------------------------------------------------------- layer 0: f16x2 emulated-fp32, 32x32x16 MFMA, 2-phase pipeline
__global__ __launch_bounds__(512, 2) void layer0_mfma(
    const half_t* __restrict__ Hch, const half_t* __restrict__ Hcl,
    half_t* __restrict__ Hnh, half_t* __restrict__ Hnl,
    const half_t* __restrict__ Wh, const half_t* __restrict__ Wl,
    const float* __restrict__ b_hh0,
    const double* __restrict__ tab,
    const int* __restrict__ x_prev,
    const int* __restrict__ list, const int* __restrict__ count) {
    int rt, ct;
    swz(blockIdx.x, rt, ct);
    const int row0 = rt * TMR;
    const int cnt = count[0];
    if (row0 >= cnt) return;

    __shared__ __align__(16) char sm[81920];
    const int tid = threadIdx.x;
    const int w = tid >> 6, l = tid & 63;
    const int l31 = l & 31, lh = l >> 5;
    const int rw = w >> 1, ch = w & 1;

    // ---- staging offsets (chunk-invariant). unit = tid (A and B round 1),
    // unit = 512+tid (B round 2, waves 0-3). unit -> (row = (u>>5)*8+(u&7),
    // kchunk = (u>>3)&3), LDS byte = unit*16, global byte = row*1024 + kchunk*16.
    const int arow = (tid >> 5) * 8 + (tid & 7);            // 0..127
    const int kch  = (tid >> 3) & 3;
    const size_t asrc = (size_t)list[row0 + arow] * 1024 + kch * 16;
    const int alds = tid * 16;
    const int b1row = arow;                                  // 0..127
    const size_t bsrc1 = (size_t)((b1row >> 6) * DH + ct * 64 + (b1row & 63)) * 1024 + kch * 16;
    const int blds1 = tid * 16;
    const int b2row = 128 + arow;                            // 128..191 (tid<256)
    const size_t bsrc2 = (size_t)((b2row >> 6) * DH + ct * 64 + (b2row & 63)) * 1024 + kch * 16;
    const int blds2 = 8192 + tid * 16;
    const bool havB2 = (tid < 256);

    // ---- fragment LDS offsets (add ks*256 per k-step)
    const int afr = rw * 32 + l31;
    const int afo = (afr >> 3) * 512 + lh * 128 + (afr & 7) * 16;
    int bfo[3];
#pragma unroll
    for (int g = 0; g < 3; ++g) {
        const int br = g * 64 + ch * 32 + l31;
        bfo[g] = (br >> 3) * 512 + lh * 128 + (br & 7) * 16;
    }

    f16v hh[3] = {}, cc[3] = {};

    auto stage = [&](int bb, int kcb) {
        const size_t ko = (size_t)kcb * 64;
        gl_lds16((const char*)Hch + asrc + ko, sm + bb + alds);
        gl_lds16((const char*)Hcl + asrc + ko, sm + bb + 8192 + alds);
        gl_lds16((const char*)Wh + bsrc1 + ko, sm + bb + 16384 + blds1);
        gl_lds16((const char*)Wl + bsrc1 + ko, sm + bb + 28672 + blds1);
        if (havB2) {
            gl_lds16((const char*)Wh + bsrc2 + ko, sm + bb + 16384 + blds2);
            gl_lds16((const char*)Wl + bsrc2 + ko, sm + bb + 28672 + blds2);
        }
    };

    stage(0, 0);
    for (int kc = 0; kc < 16; ++kc) {
        const int cb = (kc & 1) * 40960;
        if (kc < 15) {
            stage(cb ^ 40960, kc + 1);
            if (havB2) asm volatile("s_waitcnt vmcnt(6)" ::: "memory");
            else       asm volatile("s_waitcnt vmcnt(4)" ::: "memory");
        } else {
            asm volatile("s_waitcnt vmcnt(0)" ::: "memory");
        }
        __builtin_amdgcn_s_barrier();
        __builtin_amdgcn_sched_barrier(0);
        __builtin_amdgcn_s_setprio(1);
        const char* bp = sm + cb;
#pragma unroll
        for (int ks = 0; ks < 2; ++ks) {
            h8 ah = *(const h8*)(bp + afo + ks * 256);
            h8 al = *(const h8*)(bp + 8192 + afo + ks * 256);
#pragma unroll
            for (int g = 0; g < 3; ++g) {
                h8 bh = *(const h8*)(bp + 16384 + bfo[g] + ks * 256);
                h8 bl = *(const h8*)(bp + 28672 + bfo[g] + ks * 256);
                hh[g] = __builtin_amdgcn_mfma_f32_32x32x16_f16(ah, bh, hh[g], 0, 0, 0);
                cc[g] = __builtin_amdgcn_mfma_f32_32x32x16_f16(ah, bl, cc[g], 0, 0, 0);
                cc[g] = __builtin_amdgcn_mfma_f32_32x32x16_f16(al, bh, cc[g], 0, 0, 0);
            }
        }
        __builtin_amdgcn_s_setprio(0);
        asm volatile("s_waitcnt lgkmcnt(0)" ::: "memory");
        __builtin_amdgcn_s_barrier();
    }

    // ---- epilogue: C/D map (32x32): col = lane&31, row = (r&3)+8*(r>>2)+4*lh
    const int colg = ct * 64 + ch * 32 + l31;    // per-gate col 0..511
    const float inv = 1.0f / 2048.0f;
#pragma unroll
    for (int r = 0; r < 16; ++r) {
        const int la = rw * 32 + (r & 3) + 8 * (r >> 2) + 4 * lh;
        const int gi = list[row0 + la];
        const double* tr = tab + (size_t)x_prev[gi] * (3 * DH);
        float pR = hh[0][r] + cc[0][r] * inv;
        float pZ = hh[1][r] + cc[1][r] * inv;
        float pN = hh[2][r] + cc[2][r] * inv;
        float xr = (float)(tr[colg] + (double)pR + (double)b_hh0[colg]);
        float xz = (float)(tr[DH + colg] + (double)pZ + (double)b_hh0[DH + colg]);
        float hn_pre = pN + b_hh0[2 * DH + colg];
        float rg = sigf(xr), zg = sigf(xz);
        float gg = tanhf((float)(tr[2 * DH + colg] + (double)rg * (double)hn_pre));
        size_t o = (size_t)gi * DH + colg;
        float ho = rec2(Hch[o], Hcl[o]);
        float hv = (1.0f - zg) * gg + zg * ho;
        half_t oh, ol;
        split2(hv, oh, ol);
        Hnh[o] = oh; Hnl[o] = ol;
    }
}

// ---------------------------------------------------------------- layers 1/2: fused K=1024 (x-half then h-half), same structure
__global__ __launch_bounds__(512, 2) void layer12_mfma(
    const half_t* __restrict__ Xh, const half_t* __restrict__ Xl,
    const half_t* __restrict__ Hch, const half_t* __restrict__ Hcl,
    half_t* __restrict__ Hnh, half_t* __restrict__ Hnl,
    const half_t* __restrict__ Wih_h, const half_t* __restrict__ Wih_l,
    const half_t* __restrict__ Whh_h, const half_t* __restrict__ Whh_l,
    const float* __restrict__ b_ih, const float* __restrict__ b_hh,
    const int* __restrict__ list, const int* __restrict__ count) {
    int rt, ct;
    swz(blockIdx.x, rt, ct);
    const int row0 = rt * TMR;
    const int cnt = count[0];
    if (row0 >= cnt) return;

    __shared__ __align__(16) char sm[81920];
    const int tid = threadIdx.x;
    const int w = tid >> 6, l = tid & 63;
    const int l31 = l & 31, lh = l >> 5;
    const int rw = w >> 1, ch = w & 1;

    const int arow = (tid >> 5) * 8 + (tid & 7);
    const int kch  = (tid >> 3) & 3;
    const size_t asrc = (size_t)list[row0 + arow] * 1024 + kch * 16;
    const int alds = tid * 16;
    const int b1row = arow;
    const size_t bsrc1 = (size_t)((b1row >> 6) * DH + ct * 64 + (b1row & 63)) * 1024 + kch * 16;
    const int blds1 = tid * 16;
    const int b2row = 128 + arow;
    const size_t bsrc2 = (size_t)((b2row >> 6) * DH + ct * 64 + (b2row & 63)) * 1024 + kch * 16;
    const int blds2 = 8192 + tid * 16;
    const bool havB2 = (tid < 256);

    const int afr = rw * 32 + l31;
    const int afo = (afr >> 3) * 512 + lh * 128 + (afr & 7) * 16;
    int bfo[3];
#pragma unroll
    for (int g = 0; g < 3; ++g) {
        const int br = g * 64 + ch * 32 + l31;
        bfo[g] = (br >> 3) * 512 + lh * 128 + (br & 7) * 16;
    }

    f16v hh[3] = {}, cc[3] = {}, niS = {};

    auto stage = [&](int bb, int kcb) {
        const char* Ah_ = (kcb < 16) ? (const char*)Xh : (const char*)Hch;
        const char* Al_ = (kcb < 16) ? (const char*)Xl : (const char*)Hcl;
        const char* Bh_ = (kcb < 16) ? (const char*)Wih_h : (const char*)Whh_h;
        const char* Bl_ = (kcb < 16) ? (const char*)Wih_l : (const char*)Whh_l;
        const size_t ko = (size_t)(kcb & 15) * 64;
        gl_lds16(Ah_ + asrc + ko, sm + bb + alds);
        gl_lds16(Al_ + asrc + ko, sm + bb + 8192 + alds);
        gl_lds16(Bh_ + bsrc1 + ko, sm + bb + 16384 + blds1);
        gl_lds16(Bl_ + bsrc1 + ko, sm + bb + 28672 + blds1);
        if (havB2) {
            gl_lds16(Bh_ + bsrc2 + ko, sm + bb + 16384 + blds2);
            gl_lds16(Bl_ + bsrc2 + ko, sm + bb + 28672 + blds2);
        }
    };

    stage(0, 0);
    for (int kc = 0; kc < 32; ++kc) {
        const int cb = (kc & 1) * 40960;
        if (kc < 31) {
            stage(cb ^ 40960, kc + 1);
            if (havB2) asm volatile("s_waitcnt vmcnt(6)" ::: "memory");
            else       asm volatile("s_waitcnt vmcnt(4)" ::: "memory");
        } else {
            asm volatile("s_waitcnt vmcnt(0)" ::: "memory");
        }
        __builtin_amdgcn_s_barrier();
        __builtin_amdgcn_sched_barrier(0);
        __builtin_amdgcn_s_setprio(1);
        const char* bp = sm + cb;
#pragma unroll
        for (int ks = 0; ks < 2; ++ks) {
            h8 ah = *(const h8*)(bp + afo + ks * 256);
            h8 al = *(const h8*)(bp + 8192 + afo + ks * 256);
#pragma unroll
            for (int g = 0; g < 3; ++g) {
                h8 bh = *(const h8*)(bp + 16384 + bfo[g] + ks * 256);
                h8 bl = *(const h8*)(bp + 28672 + bfo[g] + ks * 256);
                hh[g] = __builtin_amdgcn_mfma_f32_32x32x16_f16(ah, bh, hh[g], 0, 0, 0);
                cc[g] = __builtin_amdgcn_mfma_f32_32x32x16_f16(ah, bl, cc[g], 0, 0, 0);
                cc[g] = __builtin_amdgcn_mfma_f32_32x32x16_f16(al, bh, cc[g], 0, 0, 0);
            }
        }
        __builtin_amdgcn_s_setprio(0);
        if (kc == 15) {
            // end of x-half: save i_n partial, reset n-gate accumulators
            niS = hh[2] + cc[2] * (1.0f / 2048.0f);
            f16v zz = {};
            hh[2] = zz; cc[2] = zz;
        }
        asm volatile("s_waitcnt lgkmcnt(0)" ::: "memory");
        __builtin_amdgcn_s_barrier();
    }

    const int colg = ct * 64 + ch * 32 + l31;
    const float inv = 1.0f / 2048.0f;
#pragma unroll
    for (int r = 0; r < 16; ++r) {
        const int la = rw * 32 + (r & 3) + 8 * (r >> 2) + 4 * lh;
        const int gi = list[row0 + la];
        float pR = hh[0][r] + cc[0][r] * inv;
        float pZ = hh[1][r] + cc[1][r] * inv;
        float pNH = hh[2][r] + cc[2][r] * inv;
        float xr = pR + b_ih[colg] + b_hh[colg];
        float xz = pZ + b_ih[DH + colg] + b_hh[DH + colg];
        float xi = niS[r] + b_ih[2 * DH + colg];
        float hn_pre = pNH + b_hh[2 * DH + colg];
        float rg = sigf(xr), zg = sigf(xz);
        float gg = tanhf(xi + rg * hn_pre);
        size_t o = (size_t)gi * DH + colg;
        float ho = rec2(Hch[o], Hcl[o]);
        float hv = (1.0f - zg) * gg + zg * ho;
        half_t oh, ol;
        split2(hv, oh, ol);
        Hnh[o] = oh; Hnl[o] = ol;
    }
}

// ---------------------------------------------------------------- logits + fp32 softmax + argmax + token update (row-indirect)
__global__ __launch_bounds__(256) void logits_kernel(const half_t* __restrict__ H2h,
                                                     const half_t* __restrict__ H2l,
                                                     const float* __restrict__ h2v_w,
                                                     const float* __restrict__ h2v_b,
                                                     int* __restrict__ x_prev,
                                                     int* __restrict__ eos,
                                                     int* __restrict__ out,
                                                     const int* __restrict__ list,
                                                     const int* __restrict__ count,
                                                     int t) {
    const int rowbase = blockIdx.x * 16;
    const int cnt = count[0];
    if (rowbase >= cnt) return;

    __shared__ float Ws[VOCAB][65];
    __shared__ float Hs[16][65];
    const int tid = threadIdx.x;
    double acc[4] = {0.0, 0.0, 0.0, 0.0};

    for (int k0 = 0; k0 < DH; k0 += 64) {
        __syncthreads();
#pragma unroll
        for (int it = 0; it < 16; ++it) {
            int idx = tid + 256 * it;
            int v = idx >> 6, k = idx & 63;
            Ws[v][k] = h2v_w[(size_t)v * DH + k0 + k];
        }
#pragma unroll
        for (int it = 0; it < 4; ++it) {
            int idx = tid + 256 * it;
            int r = idx >> 6, k = idx & 63;
            size_t o = (size_t)list[rowbase + r] * DH + k0 + k;
            Hs[r][k] = rec2(H2h[o], H2l[o]);
        }
        __syncthreads();
        const int r = tid >> 4;
        const int vb = (tid & 15) * 4;
#pragma unroll 16
        for (int k = 0; k < 64; ++k) {
            double h = (double)Hs[r][k];
            acc[0] += h * (double)Ws[vb + 0][k];
            acc[1] += h * (double)Ws[vb + 1][k];
            acc[2] += h * (double)Ws[vb + 2][k];
            acc[3] += h * (double)Ws[vb + 3][k];
        }
    }

    const int r = tid >> 4;
    const int vb = (tid & 15) * 4;
    float lf[4];
#pragma unroll
    for (int vv = 0; vv < 4; ++vv) lf[vv] = (float)(acc[vv] + (double)h2v_b[vb + vv]);

    float m = fmaxf(fmaxf(lf[0], lf[1]), fmaxf(lf[2], lf[3]));
#pragma unroll
    for (int off = 1; off < 16; off <<= 1) m = fmaxf(m, __shfl_xor(m, off));
    float e[4];
    float ssum = 0.f;
#pragma unroll
    for (int vv = 0; vv < 4; ++vv) { e[vv] = expf(lf[vv] - m); ssum += e[vv]; }
#pragma unroll
    for (int off = 1; off < 16; off <<= 1) ssum += __shfl_xor(ssum, off);

    float best = e[0] / ssum;
    int bi = vb;
#pragma unroll
    for (int vv = 1; vv < 4; ++vv) {
        float pv = e[vv] / ssum;
        if (pv > best) { best = pv; bi = vb + vv; }
    }
#pragma unroll
    for (int off = 1; off < 16; off <<= 1) {
        float ov = __shfl_xor(best, off);
        int oi = __shfl_xor(bi, off);
        if (ov > best || (ov == best && oi < bi)) { best = ov; bi = oi; }
    }
    if ((tid & 15) == 0) {
        const int gi = list[rowbase + r];
        const int ee = eos[gi];
        const int xt = bi;
        out[(size_t)gi * TMAX + t] = ee ? 0 : xt;
        if (!ee && xt == EOS_TOK) {
            out[NSEQ * TMAX + gi] = t + 1;
            eos[gi] = 1;
        }
        x_prev[gi] = xt;
    }
}

// ---------------------------------------------------------------- host
extern "C" void kernel_launch(void* const* d_in, const int* in_sizes, int n_in,
                              void* d_out, int out_size, void* d_ws, size_t ws_size,
                              hipStream_t stream) {
    const float* Z        = (const float*)d_in[0];
    const float* emb      = (const float*)d_in[1];
    const float* z2h_w    = (const float*)d_in[2];
    const float* z2h_b    = (const float*)d_in[3];
    const float* w_ih0    = (const float*)d_in[4];
    const float* w_ih_rest= (const float*)d_in[5];   // [2][1536][512]
    const float* w_hh     = (const float*)d_in[6];   // [3][1536][512]
    const float* b_ih     = (const float*)d_in[7];   // [3][1536]
    const float* b_hh     = (const float*)d_in[8];
    const float* h2v_w    = (const float*)d_in[9];
    const float* h2v_b    = (const float*)d_in[10];

    int* out = (int*)d_out;
    char* p = (char*)d_ws;
    const size_t HS = (size_t)NSEQ * DH * sizeof(half_t);   // 8 MiB per split buffer
    half_t* Bh[4]; half_t* Bl[4];
    for (int i = 0; i < 4; ++i) { Bh[i] = (half_t*)p; p += HS; }
    for (int i = 0; i < 4; ++i) { Bl[i] = (half_t*)p; p += HS; }
    double* tab = (double*)p; p += (size_t)VOCAB * 3 * DH * sizeof(double);
    const size_t WH = (size_t)3 * DH * DH;   // elems per weight matrix (1536*512)
    half_t* wih_h = (half_t*)p; p += 2 * WH * sizeof(half_t);
    half_t* wih_l = (half_t*)p; p += 2 * WH * sizeof(half_t);
    half_t* whh_h = (half_t*)p; p += 3 * WH * sizeof(half_t);
    half_t* whh_l = (half_t*)p; p += 3 * WH * sizeof(half_t);
    int* x_prev = (int*)p; p += NSEQ * sizeof(int);
    int* eos    = (int*)p; p += NSEQ * sizeof(int);
    int* alist  = (int*)p; p += NSEQ * sizeof(int);
    int* acount = (int*)p; p += 256;

    // PAD-fill token region so skipped (post-EOS) rows read as PAD=0.
    hipMemsetAsync(out, 0, (size_t)NSEQ * TMAX * sizeof(int), stream);
    init_kernel<<<NSEQ / 256, 256, 0, stream>>>(x_prev, eos, out, alist, acount);
    h0_kernel<<<NSEQ, 256, 0, stream>>>(Z, z2h_w, z2h_b,
                                        Bh[0], Bl[0], Bh[1], Bl[1], Bh[2], Bl[2]);
    gi0_kernel<<<VOCAB, 256, 0, stream>>>(emb, w_ih0, b_ih, tab);
    wsplit_kernel<<<(int)((2 * WH + 255) / 256), 256, 0, stream>>>(w_ih_rest, wih_h, wih_l, (int)(2 * WH));
    wsplit_kernel<<<(int)((3 * WH + 255) / 256), 256, 0, stream>>>(w_hh, whh_h, whh_l, (int)(3 * WH));

    int c0 = 0, c1 = 1, c2 = 2, sp = 3;
    const int lgrid = (NSEQ / TMR) * (DH / 64);   // 64 * 8 = 512 blocks, 1-D swizzled
    for (int t = 1; t < TMAX; ++t) {
        layer0_mfma<<<lgrid, 512, 0, stream>>>(Bh[c0], Bl[c0], Bh[sp], Bl[sp],
            whh_h, whh_l, b_hh, tab, x_prev, alist, acount);
        layer12_mfma<<<lgrid, 512, 0, stream>>>(Bh[sp], Bl[sp], Bh[c1], Bl[c1], Bh[c0], Bl[c0],
            wih_h, wih_l, whh_h + WH, whh_l + WH, b_ih + 3 * DH, b_hh + 3 * DH, alist, acount);
        layer12_mfma<<<lgrid, 512, 0, stream>>>(Bh[c0], Bl[c0], Bh[c2], Bl[c2], Bh[c1], Bl[c1],
            wih_h + WH, wih_l + WH, whh_h + 2 * WH, whh_l + 2 * WH,
            b_ih + 6 * DH, b_hh + 6 * DH, alist, acount);
        logits_kernel<<<NSEQ / 16, 256, 0, stream>>>(Bh[c1], Bl[c1], h2v_w, h2v_b,
                                                     x_prev, eos, out, alist, acount, t);
        if (t < TMAX - 1)
            compact_kernel<<<1, 1024, 0, stream>>>(eos, alist, acount);
        int n0 = sp, n1 = c0, n2 = c1, nsp = c2;
        c0 = n0; c1 = n1; c2 = n2; sp = nsp;
    }
}